// Round 1
// baseline (5448.378 us; speedup 1.0000x reference)
//
#include <hip/hip_runtime.h>
#include <cstdint>
#include <cstddef>

#define Lx 4
#define Bx 4
#define Tx 1024
#define Cx 1024
#define Hx 16
#define DHx 64
#define FFx 4096
#define Vx 32000
#define BTx 4096

typedef __attribute__((ext_vector_type(8))) __bf16 bf16x8;
typedef __attribute__((ext_vector_type(4))) float f32x4;

__device__ __forceinline__ float bflo(unsigned u){ return __builtin_bit_cast(float, u << 16); }
__device__ __forceinline__ float bfhi(unsigned u){ return __builtin_bit_cast(float, u & 0xffff0000u); }
__device__ __forceinline__ float bf2f(short s){ return bflo((unsigned)(unsigned short)s); }
__device__ __forceinline__ short f2bf(float f){
  unsigned u = __builtin_bit_cast(unsigned, f);
  u += 0x7fffu + ((u >> 16) & 1u);
  return (short)(u >> 16);
}

__device__ __forceinline__ void gload_lds16(const short* g, short* l){
  __builtin_amdgcn_global_load_lds(
      (const __attribute__((address_space(1))) unsigned int*)g,
      (__attribute__((address_space(3))) unsigned int*)l, 16, 0, 0);
}

// ---------------- embedding: x[bt][c] = tok_emb[idx[bt]][c] + pos_emb[t][c]
__global__ __launch_bounds__(256) void embed_kernel(
    const int* __restrict__ idx, const float* __restrict__ tok,
    const float* __restrict__ pos, float* __restrict__ x)
{
  const int bt = blockIdx.x;
  const int t  = bt & (Tx - 1);
  const int tid = threadIdx.x;
  const int tk = idx[bt];
  float4 a = *(const float4*)&tok[((size_t)tk << 10) + (tid << 2)];
  const float4 p = *(const float4*)&pos[((size_t)t << 10) + (tid << 2)];
  a.x += p.x; a.y += p.y; a.z += p.z; a.w += p.w;
  *(float4*)&x[((size_t)bt << 10) + (tid << 2)] = a;
}

// ---------------- layernorm: fp32 row -> bf16 row
__global__ __launch_bounds__(256) void ln_kernel(
    const float* __restrict__ x, const float* __restrict__ g,
    const float* __restrict__ b, short* __restrict__ out)
{
  const int row = blockIdx.x;
  const int tid = threadIdx.x;
  const float4 v = *(const float4*)&x[((size_t)row << 10) + (tid << 2)];
  float s  = v.x + v.y + v.z + v.w;
  float ss = v.x*v.x + v.y*v.y + v.z*v.z + v.w*v.w;
  #pragma unroll
  for (int off = 32; off >= 1; off >>= 1) {
    s  += __shfl_down(s, off);
    ss += __shfl_down(ss, off);
  }
  __shared__ float rs[4], rss[4];
  const int lane = tid & 63, w = tid >> 6;
  if (lane == 0) { rs[w] = s; rss[w] = ss; }
  __syncthreads();
  s  = rs[0] + rs[1] + rs[2] + rs[3];
  ss = rss[0] + rss[1] + rss[2] + rss[3];
  const float mu  = s * (1.0f / Cx);
  const float var = ss * (1.0f / Cx) - mu * mu;
  const float rstd = rsqrtf(var + 1e-5f);
  const float4 g4 = *(const float4*)&g[tid << 2];
  const float4 b4 = *(const float4*)&b[tid << 2];
  short4 o;
  o.x = f2bf((v.x - mu) * rstd * g4.x + b4.x);
  o.y = f2bf((v.y - mu) * rstd * g4.y + b4.y);
  o.z = f2bf((v.z - mu) * rstd * g4.z + b4.z);
  o.w = f2bf((v.w - mu) * rstd * g4.w + b4.w);
  *(short4*)&out[((size_t)row << 10) + (tid << 2)] = o;
}

// ---------------- weight convert+transpose: fp32 [K,N] -> bf16 [N,K]
__global__ __launch_bounds__(256) void wconv_kernel(
    const float* __restrict__ W, short* __restrict__ Wt, int K, int N)
{
  __shared__ float tile[32][33];
  const int n0 = blockIdx.x << 5, k0 = blockIdx.y << 5;
  const int tx = threadIdx.x & 31, ty = threadIdx.x >> 5;
  #pragma unroll
  for (int r = 0; r < 4; ++r)
    tile[ty + (r << 3)][tx] = W[(size_t)(k0 + ty + (r << 3)) * N + n0 + tx];
  __syncthreads();
  #pragma unroll
  for (int r = 0; r < 4; ++r)
    Wt[(size_t)(n0 + ty + (r << 3)) * K + k0 + tx] = f2bf(tile[tx][ty + (r << 3)]);
}

// ---------------- GEMM: C[M,N] = A[M,K](bf16) @ Bt[N,K](bf16)^T, m97 structure
// MODE 0: store bf16 to q/k/v layout [B,H,T,DH]
// MODE 1: outF = res + acc + bias (fp32)
// MODE 2: outB = bf16(gelu(acc + bias))
// MODE 3: outF = acc + bias (fp32)
template<int MODE>
__global__ __launch_bounds__(256) void gemm_kernel(
    const short* __restrict__ A, const short* __restrict__ Bt,
    const float* __restrict__ bias, const float* __restrict__ res,
    float* __restrict__ outF, short* __restrict__ outB, int N, int K)
{
  __shared__ __align__(16) short sA[128 * 32];
  __shared__ __align__(16) short sB[128 * 32];
  const int tid  = threadIdx.x;
  const int lane = tid & 63;
  const int wave = tid >> 6;
  const int ntile = N >> 7;
  const int tm = (int)(blockIdx.x / ntile) << 7;
  const int tn = (int)(blockIdx.x % ntile) << 7;
  const int wm = ((wave >> 1) & 1) << 6;
  const int wn = (wave & 1) << 6;

  f32x4 acc[4][4] = {};

  const int o1  = tid << 4;          // byte offset in 8KB tile
  const int row = o1 >> 6;           // tile row (64B per row of 32 bf16)
  const int col = (o1 & 63) >> 1;    // k element within row
  const short* gA1 = A  + (size_t)(tm + row) * K + col;
  const short* gA2 = A  + (size_t)(tm + row + 64) * K + col;
  const short* gB1 = Bt + (size_t)(tn + row) * K + col;
  const short* gB2 = Bt + (size_t)(tn + row + 64) * K + col;
  short* lA1 = sA + (wave << 9);
  short* lA2 = sA + 2048 + (wave << 9);
  short* lB1 = sB + (wave << 9);
  short* lB2 = sB + 2048 + (wave << 9);

  for (int k0 = 0; k0 < K; k0 += 32) {
    gload_lds16(gA1 + k0, lA1);
    gload_lds16(gA2 + k0, lA2);
    gload_lds16(gB1 + k0, lB1);
    gload_lds16(gB2 + k0, lB2);
    __syncthreads();
    bf16x8 aF[4], bF[4];
    const int kb = (lane >> 4) << 3;
    const int rsel = lane & 15;
    #pragma unroll
    for (int m = 0; m < 4; ++m)
      aF[m] = *(const bf16x8*)&sA[(wm + m * 16 + rsel) * 32 + kb];
    #pragma unroll
    for (int n = 0; n < 4; ++n)
      bF[n] = *(const bf16x8*)&sB[(wn + n * 16 + rsel) * 32 + kb];
    #pragma unroll
    for (int m = 0; m < 4; ++m) {
      #pragma unroll
      for (int n = 0; n < 4; ++n)
        acc[m][n] = __builtin_amdgcn_mfma_f32_16x16x32_bf16(aF[m], bF[n], acc[m][n], 0, 0, 0);
    }
    __syncthreads();
  }

  const int r0 = (lane >> 4) << 2;
  const int c0 = lane & 15;
  #pragma unroll
  for (int m = 0; m < 4; ++m) {
    #pragma unroll
    for (int n = 0; n < 4; ++n) {
      #pragma unroll
      for (int r = 0; r < 4; ++r) {
        const int grow = tm + wm + m * 16 + r0 + r;
        const int gcol = tn + wn + n * 16 + c0;
        const float v = acc[m][n][r];
        if constexpr (MODE == 0) {
          const int b = grow >> 10, t = grow & 1023;
          const int hh = gcol >> 6, d = gcol & 63;
          outB[((size_t)((((b << 4) + hh) << 10) + t) << 6) + d] = f2bf(v);
        } else if constexpr (MODE == 1) {
          const size_t o = (size_t)grow * N + gcol;
          outF[o] = res[o] + v + bias[gcol];
        } else if constexpr (MODE == 2) {
          const float t2 = v + bias[gcol];
          const float gl = 0.5f * t2 * (1.0f + erff(t2 * 0.7071067811865475f));
          outB[(size_t)grow * N + gcol] = f2bf(gl);
        } else {
          outF[(size_t)grow * N + gcol] = v + bias[gcol];
        }
      }
    }
  }
}

// ---------------- attention: one wave per query row; q,k,v bf16 [B,H,T,DH]
__global__ __launch_bounds__(256) void attn_kernel(
    const short* __restrict__ q, const short* __restrict__ k,
    const short* __restrict__ v, short* __restrict__ att)
{
  __shared__ __align__(16) float qs[4][64];
  __shared__ float wei[4][1024];
  const int lane = threadIdx.x & 63;
  const int w    = threadIdx.x >> 6;
  const int gw   = blockIdx.x * 4 + w;
  const int qrow = gw & (Tx - 1);
  const int bh   = gw >> 10;               // b*H + h
  const short* Kp = k + ((size_t)bh << 16);  // 1024*64
  const short* Vp = v + ((size_t)bh << 16);
  qs[w][lane] = bf2f(q[((size_t)bh << 16) + ((size_t)qrow << 6) + lane]) * 0.125f;
  __syncthreads();

  float s[16];
  float mx = -1e30f;
  #pragma unroll 4
  for (int j = 0; j < 16; ++j) {
    const int kk = (j << 6) + lane;
    float a = -1e30f;
    if (kk <= qrow) {
      a = 0.0f;
      const short* Kr = Kp + ((size_t)kk << 6);
      #pragma unroll
      for (int c = 0; c < 8; ++c) {
        const int4 raw = *(const int4*)(Kr + (c << 3));
        const float4 q0 = *(const float4*)&qs[w][(c << 3)];
        const float4 q1 = *(const float4*)&qs[w][(c << 3) + 4];
        a += bflo((unsigned)raw.x) * q0.x + bfhi((unsigned)raw.x) * q0.y
           + bflo((unsigned)raw.y) * q0.z + bfhi((unsigned)raw.y) * q0.w
           + bflo((unsigned)raw.z) * q1.x + bfhi((unsigned)raw.z) * q1.y
           + bflo((unsigned)raw.w) * q1.z + bfhi((unsigned)raw.w) * q1.w;
      }
    }
    s[j] = a;
    mx = fmaxf(mx, a);
  }
  #pragma unroll
  for (int off = 32; off >= 1; off >>= 1) mx = fmaxf(mx, __shfl_xor(mx, off));
  float sum = 0.0f;
  #pragma unroll
  for (int j = 0; j < 16; ++j) {
    float p = ((j << 6) + lane <= qrow) ? __expf(s[j] - mx) : 0.0f;
    s[j] = p; sum += p;
  }
  #pragma unroll
  for (int off = 32; off >= 1; off >>= 1) sum += __shfl_xor(sum, off);
  const float inv = 1.0f / sum;
  #pragma unroll
  for (int j = 0; j < 16; ++j) wei[w][(j << 6) + lane] = s[j] * inv;
  __syncthreads();

  // PV: lane = d, coalesced V reads, broadcast wei reads
  float acc = 0.0f;
  int kk = 0;
  const int kend = qrow + 1;
  for (; kk + 4 <= kend; kk += 4) {
    const float w0 = wei[w][kk], w1 = wei[w][kk + 1], w2 = wei[w][kk + 2], w3 = wei[w][kk + 3];
    acc += w0 * bf2f(Vp[((size_t)(kk    ) << 6) + lane]);
    acc += w1 * bf2f(Vp[((size_t)(kk + 1) << 6) + lane]);
    acc += w2 * bf2f(Vp[((size_t)(kk + 2) << 6) + lane]);
    acc += w3 * bf2f(Vp[((size_t)(kk + 3) << 6) + lane]);
  }
  for (; kk < kend; ++kk) acc += wei[w][kk] * bf2f(Vp[((size_t)kk << 6) + lane]);

  const int b = bh >> 4, hh = bh & 15;
  att[((size_t)((b << 10) + qrow) << 10) + (hh << 6) + lane] = f2bf(acc);
}

// ---------------- cross-entropy
__global__ void ce_zero_kernel(float* accum){ accum[0] = 0.0f; accum[1] = 0.0f; }

__global__ __launch_bounds__(256) void ce_row_kernel(
    const float* __restrict__ logits, const int* __restrict__ tgt, float* __restrict__ accum)
{
  const int row = blockIdx.x;
  const float* lg = logits + (size_t)row * Vx;
  const int tid = threadIdx.x;
  float m = -1e30f, ssum = 0.0f;
  for (int i = tid; i < Vx; i += 256) {
    const float v2 = lg[i];
    const float nm = fmaxf(m, v2);
    ssum = ssum * __expf(m - nm) + __expf(v2 - nm);
    m = nm;
  }
  #pragma unroll
  for (int off = 32; off >= 1; off >>= 1) {
    const float om = __shfl_down(m, off), os = __shfl_down(ssum, off);
    const float nm = fmaxf(m, om);
    ssum = ssum * __expf(m - nm) + os * __expf(om - nm);
    m = nm;
  }
  __shared__ float ms[4], sss[4];
  if ((tid & 63) == 0) { ms[tid >> 6] = m; sss[tid >> 6] = ssum; }
  __syncthreads();
  if (tid == 0) {
    float M = ms[0], S = sss[0];
    #pragma unroll
    for (int i = 1; i < 4; ++i) {
      const float nm = fmaxf(M, ms[i]);
      S = S * __expf(M - nm) + sss[i] * __expf(ms[i] - nm);
      M = nm;
    }
    const int tg = tgt[row];
    if (tg != 5) {
      const float lt = lg[tg];
      const float nll = -(lt - M - logf(S));
      atomicAdd(&accum[0], nll);
      atomicAdd(&accum[1], 1.0f);
    }
  }
}

__global__ void ce_final_kernel(const float* __restrict__ accum, float* __restrict__ out)
{
  out[131072000ull] = accum[0] / fmaxf(accum[1], 1.0f);
}

// ---------------- host
extern "C" void kernel_launch(void* const* d_in, const int* in_sizes, int n_in,
                              void* d_out, int out_size, void* d_ws, size_t ws_size,
                              hipStream_t stream)
{
  const int*   idx     = (const int*)d_in[0];
  const int*   targets = (const int*)d_in[1];
  const float* tok_emb = (const float*)d_in[2];
  const float* pos_emb = (const float*)d_in[3];
  const float* Wq      = (const float*)d_in[4];
  const float* Wk      = (const float*)d_in[5];
  const float* Wv      = (const float*)d_in[6];
  const float* Wo      = (const float*)d_in[7];
  const float* bo      = (const float*)d_in[8];
  const float* ln1_g   = (const float*)d_in[9];
  const float* ln1_b   = (const float*)d_in[10];
  const float* ln2_g   = (const float*)d_in[11];
  const float* ln2_b   = (const float*)d_in[12];
  const float* W1      = (const float*)d_in[13];
  const float* b1      = (const float*)d_in[14];
  const float* W2      = (const float*)d_in[15];
  const float* b2      = (const float*)d_in[16];
  const float* lnf_g   = (const float*)d_in[17];
  const float* lnf_b   = (const float*)d_in[18];
  const float* Whead   = (const float*)d_in[19];
  const float* bhead   = (const float*)d_in[20];
  float* out = (float*)d_out;

  char* ws = (char*)d_ws;
  size_t off = 0;
  auto alloc = [&](size_t bytes) -> char* {
    char* p = ws + off;
    off += (bytes + 255) & ~(size_t)255;
    return p;
  };
  float* x    = (float*)alloc((size_t)BTx * Cx * 4);   // fp32 residual stream
  short* h    = (short*)alloc((size_t)BTx * Cx * 2);   // bf16 LN output
  char*  blk  = ws + off;                              // overlay region start
  short* qb   = (short*)alloc((size_t)BTx * Cx * 2);
  short* kb   = (short*)alloc((size_t)BTx * Cx * 2);
  short* vb   = (short*)alloc((size_t)BTx * Cx * 2);
  short* attb = (short*)alloc((size_t)BTx * Cx * 2);
  short* ffb  = (short*)alloc((size_t)BTx * FFx * 2);
  short* wheadT = (short*)blk;                         // 65.5MB overlaid on q..ff (67.1MB)
  short* wqT  = (short*)alloc((size_t)Cx * Cx * 2);
  short* wkT  = (short*)alloc((size_t)Cx * Cx * 2);
  short* wvT  = (short*)alloc((size_t)Cx * Cx * 2);
  short* woT  = (short*)alloc((size_t)Cx * Cx * 2);
  short* w1T  = (short*)alloc((size_t)Cx * FFx * 2);
  short* w2T  = (short*)alloc((size_t)FFx * Cx * 2);
  float* accum = (float*)alloc(256);
  if (ws_size < off) return;  // workspace too small: fail loudly via wrong output

  embed_kernel<<<BTx, 256, 0, stream>>>(idx, tok_emb, pos_emb, x);
  ce_zero_kernel<<<1, 1, 0, stream>>>(accum);

  for (int i = 0; i < Lx; ++i) {
    const size_t wo_off = (size_t)i * Cx * Cx;
    const size_t w1_off = (size_t)i * Cx * FFx;
    wconv_kernel<<<dim3(Cx / 32, Cx / 32), 256, 0, stream>>>(Wq + wo_off, wqT, Cx, Cx);
    wconv_kernel<<<dim3(Cx / 32, Cx / 32), 256, 0, stream>>>(Wk + wo_off, wkT, Cx, Cx);
    wconv_kernel<<<dim3(Cx / 32, Cx / 32), 256, 0, stream>>>(Wv + wo_off, wvT, Cx, Cx);
    wconv_kernel<<<dim3(Cx / 32, Cx / 32), 256, 0, stream>>>(Wo + wo_off, woT, Cx, Cx);
    wconv_kernel<<<dim3(FFx / 32, Cx / 32), 256, 0, stream>>>(W1 + w1_off, w1T, Cx, FFx);
    wconv_kernel<<<dim3(Cx / 32, FFx / 32), 256, 0, stream>>>(W2 + w1_off, w2T, FFx, Cx);

    ln_kernel<<<BTx, 256, 0, stream>>>(x, ln1_g + i * Cx, ln1_b + i * Cx, h);
    gemm_kernel<0><<<(BTx / 128) * (Cx / 128), 256, 0, stream>>>(h, wqT, nullptr, nullptr, nullptr, qb, Cx, Cx);
    gemm_kernel<0><<<(BTx / 128) * (Cx / 128), 256, 0, stream>>>(h, wkT, nullptr, nullptr, nullptr, kb, Cx, Cx);
    gemm_kernel<0><<<(BTx / 128) * (Cx / 128), 256, 0, stream>>>(h, wvT, nullptr, nullptr, nullptr, vb, Cx, Cx);
    attn_kernel<<<(Bx * Hx * Tx) / 4, 256, 0, stream>>>(qb, kb, vb, attb);
    gemm_kernel<1><<<(BTx / 128) * (Cx / 128), 256, 0, stream>>>(attb, woT, bo + i * Cx, x, x, nullptr, Cx, Cx);

    ln_kernel<<<BTx, 256, 0, stream>>>(x, ln2_g + i * Cx, ln2_b + i * Cx, h);
    gemm_kernel<2><<<(BTx / 128) * (FFx / 128), 256, 0, stream>>>(h, w1T, b1 + i * FFx, nullptr, nullptr, ffb, FFx, Cx);
    gemm_kernel<1><<<(BTx / 128) * (Cx / 128), 256, 0, stream>>>(ffb, w2T, b2 + i * Cx, x, x, nullptr, Cx, FFx);
  }

  ln_kernel<<<BTx, 256, 0, stream>>>(x, lnf_g, lnf_b, h);
  wconv_kernel<<<dim3(Vx / 32, Cx / 32), 256, 0, stream>>>(Whead, wheadT, Cx, Vx);
  gemm_kernel<3><<<(BTx / 128) * (Vx / 128), 256, 0, stream>>>(h, wheadT, bhead, nullptr, out, nullptr, Vx, Cx);

  ce_row_kernel<<<BTx, 256, 0, stream>>>(out, targets, accum);
  ce_final_kernel<<<1, 1, 0, stream>>>(accum, out);
}

// Round 2
// 2187.341 us; speedup vs baseline: 2.4909x; 2.4909x over previous
//
#include <hip/hip_runtime.h>
#include <cstdint>
#include <cstddef>

#define Lx 4
#define Bx 4
#define Tx 1024
#define Cx 1024
#define Hx 16
#define DHx 64
#define FFx 4096
#define Vx 32000
#define BTx 4096

typedef __attribute__((ext_vector_type(8))) __bf16 bf16x8;
typedef __attribute__((ext_vector_type(4))) float f32x4;
typedef __attribute__((ext_vector_type(8))) short short8;

__device__ __forceinline__ float bflo(unsigned u){ return __builtin_bit_cast(float, u << 16); }
__device__ __forceinline__ float bfhi(unsigned u){ return __builtin_bit_cast(float, u & 0xffff0000u); }
__device__ __forceinline__ float bf2f(short s){ return bflo((unsigned)(unsigned short)s); }
__device__ __forceinline__ short f2bf(float f){
  unsigned u = __builtin_bit_cast(unsigned, f);
  u += 0x7fffu + ((u >> 16) & 1u);
  return (short)(u >> 16);
}

__device__ __forceinline__ void gload_lds16(const short* g, short* l){
  __builtin_amdgcn_global_load_lds(
      (const __attribute__((address_space(1))) unsigned int*)g,
      (__attribute__((address_space(3))) unsigned int*)l, 16, 0, 0);
}

// ---------------- embedding
__global__ __launch_bounds__(256) void embed_kernel(
    const int* __restrict__ idx, const float* __restrict__ tok,
    const float* __restrict__ pos, float* __restrict__ x)
{
  const int bt = blockIdx.x;
  const int t  = bt & (Tx - 1);
  const int tid = threadIdx.x;
  const int tk = idx[bt];
  float4 a = *(const float4*)&tok[((size_t)tk << 10) + (tid << 2)];
  const float4 p = *(const float4*)&pos[((size_t)t << 10) + (tid << 2)];
  a.x += p.x; a.y += p.y; a.z += p.z; a.w += p.w;
  *(float4*)&x[((size_t)bt << 10) + (tid << 2)] = a;
}

// ---------------- layernorm: fp32 row -> bf16 row
__global__ __launch_bounds__(256) void ln_kernel(
    const float* __restrict__ x, const float* __restrict__ g,
    const float* __restrict__ b, short* __restrict__ out)
{
  const int row = blockIdx.x;
  const int tid = threadIdx.x;
  const float4 v = *(const float4*)&x[((size_t)row << 10) + (tid << 2)];
  float s  = v.x + v.y + v.z + v.w;
  float ss = v.x*v.x + v.y*v.y + v.z*v.z + v.w*v.w;
  #pragma unroll
  for (int off = 32; off >= 1; off >>= 1) {
    s  += __shfl_down(s, off);
    ss += __shfl_down(ss, off);
  }
  __shared__ float rs[4], rss[4];
  const int lane = tid & 63, w = tid >> 6;
  if (lane == 0) { rs[w] = s; rss[w] = ss; }
  __syncthreads();
  s  = rs[0] + rs[1] + rs[2] + rs[3];
  ss = rss[0] + rss[1] + rss[2] + rss[3];
  const float mu  = s * (1.0f / Cx);
  const float var = ss * (1.0f / Cx) - mu * mu;
  const float rstd = rsqrtf(var + 1e-5f);
  const float4 g4 = *(const float4*)&g[tid << 2];
  const float4 b4 = *(const float4*)&b[tid << 2];
  short4 o;
  o.x = f2bf((v.x - mu) * rstd * g4.x + b4.x);
  o.y = f2bf((v.y - mu) * rstd * g4.y + b4.y);
  o.z = f2bf((v.z - mu) * rstd * g4.z + b4.z);
  o.w = f2bf((v.w - mu) * rstd * g4.w + b4.w);
  *(short4*)&out[((size_t)row << 10) + (tid << 2)] = o;
}

// ---------------- weight convert+transpose: fp32 [K,N] -> bf16 [N,K]
__global__ __launch_bounds__(256) void wconv_kernel(
    const float* __restrict__ W, short* __restrict__ Wt, int K, int N)
{
  __shared__ float tile[32][33];
  const int n0 = blockIdx.x << 5, k0 = blockIdx.y << 5;
  const int tx = threadIdx.x & 31, ty = threadIdx.x >> 5;
  #pragma unroll
  for (int r = 0; r < 4; ++r)
    tile[ty + (r << 3)][tx] = W[(size_t)(k0 + ty + (r << 3)) * N + n0 + tx];
  __syncthreads();
  #pragma unroll
  for (int r = 0; r < 4; ++r)
    Wt[(size_t)(n0 + ty + (r << 3)) * K + k0 + tx] = f2bf(tile[tx][ty + (r << 3)]);
}

// ---------------- GEMM (m97 structure), modes as before
template<int MODE>
__global__ __launch_bounds__(256) void gemm_kernel(
    const short* __restrict__ A, const short* __restrict__ Bt,
    const float* __restrict__ bias, const float* __restrict__ res,
    float* __restrict__ outF, short* __restrict__ outB, int N, int K)
{
  __shared__ __align__(16) short sA[128 * 32];
  __shared__ __align__(16) short sB[128 * 32];
  const int tid  = threadIdx.x;
  const int lane = tid & 63;
  const int wave = tid >> 6;
  const int ntile = N >> 7;
  const int tm = (int)(blockIdx.x / ntile) << 7;
  const int tn = (int)(blockIdx.x % ntile) << 7;
  const int wm = ((wave >> 1) & 1) << 6;
  const int wn = (wave & 1) << 6;

  f32x4 acc[4][4] = {};

  const int o1  = tid << 4;
  const int row = o1 >> 6;
  const int col = (o1 & 63) >> 1;
  const short* gA1 = A  + (size_t)(tm + row) * K + col;
  const short* gA2 = A  + (size_t)(tm + row + 64) * K + col;
  const short* gB1 = Bt + (size_t)(tn + row) * K + col;
  const short* gB2 = Bt + (size_t)(tn + row + 64) * K + col;
  short* lA1 = sA + (wave << 9);
  short* lA2 = sA + 2048 + (wave << 9);
  short* lB1 = sB + (wave << 9);
  short* lB2 = sB + 2048 + (wave << 9);

  for (int k0 = 0; k0 < K; k0 += 32) {
    gload_lds16(gA1 + k0, lA1);
    gload_lds16(gA2 + k0, lA2);
    gload_lds16(gB1 + k0, lB1);
    gload_lds16(gB2 + k0, lB2);
    __syncthreads();
    bf16x8 aF[4], bF[4];
    const int kb = (lane >> 4) << 3;
    const int rsel = lane & 15;
    #pragma unroll
    for (int m = 0; m < 4; ++m)
      aF[m] = *(const bf16x8*)&sA[(wm + m * 16 + rsel) * 32 + kb];
    #pragma unroll
    for (int n = 0; n < 4; ++n)
      bF[n] = *(const bf16x8*)&sB[(wn + n * 16 + rsel) * 32 + kb];
    #pragma unroll
    for (int m = 0; m < 4; ++m) {
      #pragma unroll
      for (int n = 0; n < 4; ++n)
        acc[m][n] = __builtin_amdgcn_mfma_f32_16x16x32_bf16(aF[m], bF[n], acc[m][n], 0, 0, 0);
    }
    __syncthreads();
  }

  const int r0 = (lane >> 4) << 2;
  const int c0 = lane & 15;
  #pragma unroll
  for (int m = 0; m < 4; ++m) {
    #pragma unroll
    for (int n = 0; n < 4; ++n) {
      #pragma unroll
      for (int r = 0; r < 4; ++r) {
        const int grow = tm + wm + m * 16 + r0 + r;
        const int gcol = tn + wn + n * 16 + c0;
        const float v = acc[m][n][r];
        if constexpr (MODE == 0) {
          const int b = grow >> 10, t = grow & 1023;
          const int hh = gcol >> 6, d = gcol & 63;
          outB[((size_t)((((b << 4) + hh) << 10) + t) << 6) + d] = f2bf(v);
        } else if constexpr (MODE == 1) {
          const size_t o = (size_t)grow * N + gcol;
          outF[o] = res[o] + v + bias[gcol];
        } else if constexpr (MODE == 2) {
          const float t2 = v + bias[gcol];
          const float gl = 0.5f * t2 * (1.0f + erff(t2 * 0.7071067811865475f));
          outB[(size_t)grow * N + gcol] = f2bf(gl);
        } else {
          outF[(size_t)grow * N + gcol] = v + bias[gcol];
        }
      }
    }
  }
}

// ---------------- flash attention (MFMA): q,k,v bf16 [B,H,T,DH] -> att [B,T,C]
// Block: one (b,h), 64 q-rows, 4 waves x 16 q-rows. KV tiles of 64, causal.
__global__ __launch_bounds__(256) void fattn_kernel(
    const short* __restrict__ q, const short* __restrict__ k,
    const short* __restrict__ v, short* __restrict__ att)
{
  __shared__ __align__(16) short sQ[4096];     // 64x64 bf16, XOR-swizzled
  __shared__ __align__(16) short sK[4096];     // 64x64 bf16, XOR-swizzled
  __shared__ __align__(16) short sVT[4096];    // V^T [dh][kv], XOR-swizzled
  __shared__ __align__(16) short sP[4][1024];  // per-wave P 16x64, XOR-swizzled

  const int tid  = threadIdx.x;
  const int lane = tid & 63;
  const int w    = tid >> 6;
  const int r15  = lane & 15;
  const int g4   = lane >> 4;
  const int qt   = blockIdx.x & 15;
  const int bh   = blockIdx.x >> 4;

  const char* Qb = (const char*)(q + ((size_t)bh << 16)) + ((size_t)qt << 13);
  const char* Kb = (const char*)(k + ((size_t)bh << 16));
  const char* Vb = (const char*)(v + ((size_t)bh << 16));

  // pre-swizzled global source offsets for global_load_lds staging (m173 pattern)
  const int X0  = tid << 4;
  const int X1  = X0 + 4096;
  const int sw0 = X0 ^ (((X0 >> 7) & 7) << 4);
  const int sw1 = X1 ^ (((X1 >> 7) & 7) << 4);
  const int ldsOff0 = (w << 10);          // wave-uniform LDS byte base, shot 0
  const int ldsOff1 = (w << 10) + 4096;   // shot 1

  // ---- stage Q (once), read Q fragments to registers
  gload_lds16((const short*)(Qb + sw0), (short*)((char*)sQ + ldsOff0));
  gload_lds16((const short*)(Qb + sw1), (short*)((char*)sQ + ldsOff1));
  __syncthreads();
  bf16x8 aQ[2];
  {
    const int qrow = (w << 4) + r15;
    const int base = qrow * 128 + (g4 << 4);
    const int sz = (qrow & 7) << 4;
    aQ[0] = *(const bf16x8*)((char*)sQ + ((base     ) ^ sz));
    aQ[1] = *(const bf16x8*)((char*)sQ + ((base + 64) ^ sz));
  }

  // V^T staging assignment: this thread owns dh=vdh,vdh+1 x kv=[vkv0,vkv0+8)
  const int vdh  = (lane & 31) << 1;
  const int vkv0 = (((w << 1) + (lane >> 5)) << 3);
  const int vb0  = (vdh * 128 + vkv0 * 2)       ^ ((vdh & 7) << 4);
  const int vb1  = ((vdh + 1) * 128 + vkv0 * 2) ^ (((vdh + 1) & 7) << 4);

  float m[4] = {-3e38f, -3e38f, -3e38f, -3e38f};
  float l[4] = {0.f, 0.f, 0.f, 0.f};
  f32x4 acc_o[4] = {};
  const int qrow_g0 = (qt << 6) + (w << 4) + (g4 << 2);

  for (int kt = 0; kt <= qt; ++kt) {
    __syncthreads();  // prior iter done reading sK/sVT
    // stage K tile (contiguous 8KB) via global_load_lds, pre-swizzled source
    const char* Kt = Kb + ((size_t)kt << 13);
    gload_lds16((const short*)(Kt + sw0), (short*)((char*)sK + ldsOff0));
    gload_lds16((const short*)(Kt + sw1), (short*)((char*)sK + ldsOff1));
    // stage V^T via registers (coalesced reads, swizzled b128 writes)
    {
      const char* Vt = Vb + ((size_t)kt << 13);
      unsigned uv[8];
      #pragma unroll
      for (int j = 0; j < 8; ++j)
        uv[j] = *(const unsigned*)(Vt + ((vkv0 + j) << 7) + (vdh << 1));
      short8 plo, phi;
      #pragma unroll
      for (int j = 0; j < 8; ++j) {
        plo[j] = (short)(uv[j] & 0xffffu);
        phi[j] = (short)(uv[j] >> 16);
      }
      *(short8*)((char*)sVT + vb0) = plo;
      *(short8*)((char*)sVT + vb1) = phi;
    }
    __syncthreads();  // staging complete

    // ---- S = Q K^T for this wave's 16 q-rows
    f32x4 s[4] = {};
    #pragma unroll
    for (int f = 0; f < 4; ++f) {
      const int kv = (f << 4) + r15;
      const int kb = kv * 128 + (g4 << 4);
      const int sz = (kv & 7) << 4;
      const bf16x8 b0 = *(const bf16x8*)((char*)sK + ((kb     ) ^ sz));
      const bf16x8 b1 = *(const bf16x8*)((char*)sK + ((kb + 64) ^ sz));
      s[f] = __builtin_amdgcn_mfma_f32_16x16x32_bf16(aQ[0], b0, s[f], 0, 0, 0);
      s[f] = __builtin_amdgcn_mfma_f32_16x16x32_bf16(aQ[1], b1, s[f], 0, 0, 0);
    }
    // scale + causal mask
    #pragma unroll
    for (int f = 0; f < 4; ++f) {
      #pragma unroll
      for (int r = 0; r < 4; ++r) {
        float sv = s[f][r] * 0.125f;
        if ((kt << 6) + (f << 4) + r15 > qrow_g0 + r) sv = -3e38f;
        s[f][r] = sv;
      }
    }
    // ---- online softmax (per q-row: 4 frags in-reg + 16-lane group shuffles)
    #pragma unroll
    for (int r = 0; r < 4; ++r) {
      float mx = fmaxf(fmaxf(s[0][r], s[1][r]), fmaxf(s[2][r], s[3][r]));
      mx = fmaxf(mx, __shfl_xor(mx, 1));
      mx = fmaxf(mx, __shfl_xor(mx, 2));
      mx = fmaxf(mx, __shfl_xor(mx, 4));
      mx = fmaxf(mx, __shfl_xor(mx, 8));
      const float mn = fmaxf(m[r], mx);
      const float e  = __expf(m[r] - mn);
      float sum = 0.f;
      #pragma unroll
      for (int f = 0; f < 4; ++f) {
        const float p = __expf(s[f][r] - mn);
        s[f][r] = p; sum += p;
      }
      sum += __shfl_xor(sum, 1);
      sum += __shfl_xor(sum, 2);
      sum += __shfl_xor(sum, 4);
      sum += __shfl_xor(sum, 8);
      l[r] = l[r] * e + sum;
      m[r] = mn;
      acc_o[0][r] *= e; acc_o[1][r] *= e; acc_o[2][r] *= e; acc_o[3][r] *= e;
    }
    // ---- P -> LDS (bf16, swizzled), per-wave tile
    short* Pw = sP[w];
    #pragma unroll
    for (int f = 0; f < 4; ++f) {
      #pragma unroll
      for (int r = 0; r < 4; ++r) {
        const int row = (g4 << 2) + r;
        const int byte = row * 128 + (((f << 4) + r15) << 1);
        *(short*)((char*)Pw + (byte ^ ((row & 7) << 4))) = f2bf(s[f][r]);
      }
    }
    // ---- O += P V
    #pragma unroll
    for (int ks = 0; ks < 2; ++ks) {
      const int ab = r15 * 128 + (ks << 6) + (g4 << 4);
      const bf16x8 aP = *(const bf16x8*)((char*)Pw + (ab ^ ((r15 & 7) << 4)));
      #pragma unroll
      for (int f = 0; f < 4; ++f) {
        const int dh = (f << 4) + r15;
        const int bb = dh * 128 + (ks << 6) + (g4 << 4);
        const bf16x8 bV = *(const bf16x8*)((char*)sVT + (bb ^ ((dh & 7) << 4)));
        acc_o[f] = __builtin_amdgcn_mfma_f32_16x16x32_bf16(aP, bV, acc_o[f], 0, 0, 0);
      }
    }
  }

  // ---- write O / l to att [B,T,C]
  const int b = bh >> 4, hh = bh & 15;
  #pragma unroll
  for (int f = 0; f < 4; ++f) {
    #pragma unroll
    for (int r = 0; r < 4; ++r) {
      const int qg = qrow_g0 + r;
      const int dh = (f << 4) + r15;
      att[((size_t)((b << 10) + qg) << 10) + (hh << 6) + dh] = f2bf(acc_o[f][r] / l[r]);
    }
  }
}

// ---------------- cross-entropy
__global__ void ce_zero_kernel(float* accum){ accum[0] = 0.0f; accum[1] = 0.0f; }

__global__ __launch_bounds__(256) void ce_row_kernel(
    const float* __restrict__ logits, const int* __restrict__ tgt, float* __restrict__ accum)
{
  const int row = blockIdx.x;
  const float* lg = logits + (size_t)row * Vx;
  const int tid = threadIdx.x;
  float m = -1e30f, ssum = 0.0f;
  for (int i = tid; i < Vx; i += 256) {
    const float v2 = lg[i];
    const float nm = fmaxf(m, v2);
    ssum = ssum * __expf(m - nm) + __expf(v2 - nm);
    m = nm;
  }
  #pragma unroll
  for (int off = 32; off >= 1; off >>= 1) {
    const float om = __shfl_down(m, off), os = __shfl_down(ssum, off);
    const float nm = fmaxf(m, om);
    ssum = ssum * __expf(m - nm) + os * __expf(om - nm);
    m = nm;
  }
  __shared__ float ms[4], sss[4];
  if ((tid & 63) == 0) { ms[tid >> 6] = m; sss[tid >> 6] = ssum; }
  __syncthreads();
  if (tid == 0) {
    float M = ms[0], S = sss[0];
    #pragma unroll
    for (int i = 1; i < 4; ++i) {
      const float nm = fmaxf(M, ms[i]);
      S = S * __expf(M - nm) + sss[i] * __expf(ms[i] - nm);
      M = nm;
    }
    const int tg = tgt[row];
    if (tg != 5) {
      const float lt = lg[tg];
      const float nll = -(lt - M - logf(S));
      atomicAdd(&accum[0], nll);
      atomicAdd(&accum[1], 1.0f);
    }
  }
}

__global__ void ce_final_kernel(const float* __restrict__ accum, float* __restrict__ out)
{
  out[131072000ull] = accum[0] / fmaxf(accum[1], 1.0f);
}

// ---------------- host
extern "C" void kernel_launch(void* const* d_in, const int* in_sizes, int n_in,
                              void* d_out, int out_size, void* d_ws, size_t ws_size,
                              hipStream_t stream)
{
  const int*   idx     = (const int*)d_in[0];
  const int*   targets = (const int*)d_in[1];
  const float* tok_emb = (const float*)d_in[2];
  const float* pos_emb = (const float*)d_in[3];
  const float* Wq      = (const float*)d_in[4];
  const float* Wk      = (const float*)d_in[5];
  const float* Wv      = (const float*)d_in[6];
  const float* Wo      = (const float*)d_in[7];
  const float* bo      = (const float*)d_in[8];
  const float* ln1_g   = (const float*)d_in[9];
  const float* ln1_b   = (const float*)d_in[10];
  const float* ln2_g   = (const float*)d_in[11];
  const float* ln2_b   = (const float*)d_in[12];
  const float* W1      = (const float*)d_in[13];
  const float* b1      = (const float*)d_in[14];
  const float* W2      = (const float*)d_in[15];
  const float* b2      = (const float*)d_in[16];
  const float* lnf_g   = (const float*)d_in[17];
  const float* lnf_b   = (const float*)d_in[18];
  const float* Whead   = (const float*)d_in[19];
  const float* bhead   = (const float*)d_in[20];
  float* out = (float*)d_out;

  char* ws = (char*)d_ws;
  size_t off = 0;
  auto alloc = [&](size_t bytes) -> char* {
    char* p = ws + off;
    off += (bytes + 255) & ~(size_t)255;
    return p;
  };
  float* x    = (float*)alloc((size_t)BTx * Cx * 4);
  short* h    = (short*)alloc((size_t)BTx * Cx * 2);
  char*  blk  = ws + off;
  short* qb   = (short*)alloc((size_t)BTx * Cx * 2);
  short* kb   = (short*)alloc((size_t)BTx * Cx * 2);
  short* vb   = (short*)alloc((size_t)BTx * Cx * 2);
  short* attb = (short*)alloc((size_t)BTx * Cx * 2);
  short* ffb  = (short*)alloc((size_t)BTx * FFx * 2);
  short* wheadT = (short*)blk;
  short* wqT  = (short*)alloc((size_t)Cx * Cx * 2);
  short* wkT  = (short*)alloc((size_t)Cx * Cx * 2);
  short* wvT  = (short*)alloc((size_t)Cx * Cx * 2);
  short* woT  = (short*)alloc((size_t)Cx * Cx * 2);
  short* w1T  = (short*)alloc((size_t)Cx * FFx * 2);
  short* w2T  = (short*)alloc((size_t)FFx * Cx * 2);
  float* accum = (float*)alloc(256);
  if (ws_size < off) return;

  embed_kernel<<<BTx, 256, 0, stream>>>(idx, tok_emb, pos_emb, x);
  ce_zero_kernel<<<1, 1, 0, stream>>>(accum);

  for (int i = 0; i < Lx; ++i) {
    const size_t wo_off = (size_t)i * Cx * Cx;
    const size_t w1_off = (size_t)i * Cx * FFx;
    wconv_kernel<<<dim3(Cx / 32, Cx / 32), 256, 0, stream>>>(Wq + wo_off, wqT, Cx, Cx);
    wconv_kernel<<<dim3(Cx / 32, Cx / 32), 256, 0, stream>>>(Wk + wo_off, wkT, Cx, Cx);
    wconv_kernel<<<dim3(Cx / 32, Cx / 32), 256, 0, stream>>>(Wv + wo_off, wvT, Cx, Cx);
    wconv_kernel<<<dim3(Cx / 32, Cx / 32), 256, 0, stream>>>(Wo + wo_off, woT, Cx, Cx);
    wconv_kernel<<<dim3(FFx / 32, Cx / 32), 256, 0, stream>>>(W1 + w1_off, w1T, Cx, FFx);
    wconv_kernel<<<dim3(Cx / 32, FFx / 32), 256, 0, stream>>>(W2 + w1_off, w2T, FFx, Cx);

    ln_kernel<<<BTx, 256, 0, stream>>>(x, ln1_g + i * Cx, ln1_b + i * Cx, h);
    gemm_kernel<0><<<(BTx / 128) * (Cx / 128), 256, 0, stream>>>(h, wqT, nullptr, nullptr, nullptr, qb, Cx, Cx);
    gemm_kernel<0><<<(BTx / 128) * (Cx / 128), 256, 0, stream>>>(h, wkT, nullptr, nullptr, nullptr, kb, Cx, Cx);
    gemm_kernel<0><<<(BTx / 128) * (Cx / 128), 256, 0, stream>>>(h, wvT, nullptr, nullptr, nullptr, vb, Cx, Cx);
    fattn_kernel<<<Bx * Hx * (Tx / 64), 256, 0, stream>>>(qb, kb, vb, attb);
    gemm_kernel<1><<<(BTx / 128) * (Cx / 128), 256, 0, stream>>>(attb, woT, bo + i * Cx, x, x, nullptr, Cx, Cx);

    ln_kernel<<<BTx, 256, 0, stream>>>(x, ln2_g + i * Cx, ln2_b + i * Cx, h);
    gemm_kernel<2><<<(BTx / 128) * (FFx / 128), 256, 0, stream>>>(h, w1T, b1 + i * FFx, nullptr, nullptr, ffb, FFx, Cx);
    gemm_kernel<1><<<(BTx / 128) * (Cx / 128), 256, 0, stream>>>(ffb, w2T, b2 + i * Cx, x, x, nullptr, Cx, FFx);
  }

  ln_kernel<<<BTx, 256, 0, stream>>>(x, lnf_g, lnf_b, h);
  wconv_kernel<<<dim3(Vx / 32, Cx / 32), 256, 0, stream>>>(Whead, wheadT, Cx, Vx);
  gemm_kernel<3><<<(BTx / 128) * (Vx / 128), 256, 0, stream>>>(h, wheadT, bhead, nullptr, out, nullptr, Vx, Cx);

  ce_row_kernel<<<BTx, 256, 0, stream>>>(out, targets, accum);
  ce_final_kernel<<<1, 1, 0, stream>>>(accum, out);
}

// Round 3
// 1934.371 us; speedup vs baseline: 2.8166x; 1.1308x over previous
//
#include <hip/hip_runtime.h>
#include <cstdint>
#include <cstddef>

#define Lx 4
#define Bx 4
#define Tx 1024
#define Cx 1024
#define Hx 16
#define DHx 64
#define FFx 4096
#define Vx 32000
#define BTx 4096

typedef __attribute__((ext_vector_type(8))) __bf16 bf16x8;
typedef __attribute__((ext_vector_type(4))) float f32x4;
typedef __attribute__((ext_vector_type(8))) short short8;

__device__ __forceinline__ float bflo(unsigned u){ return __builtin_bit_cast(float, u << 16); }
__device__ __forceinline__ float bfhi(unsigned u){ return __builtin_bit_cast(float, u & 0xffff0000u); }
__device__ __forceinline__ float bf2f(short s){ return bflo((unsigned)(unsigned short)s); }
__device__ __forceinline__ short f2bf(float f){
  unsigned u = __builtin_bit_cast(unsigned, f);
  u += 0x7fffu + ((u >> 16) & 1u);
  return (short)(u >> 16);
}

__device__ __forceinline__ void gload_lds16(const short* g, short* l){
  __builtin_amdgcn_global_load_lds(
      (const __attribute__((address_space(1))) unsigned int*)g,
      (__attribute__((address_space(3))) unsigned int*)l, 16, 0, 0);
}

// bijective chunked XCD swizzle (m204): contiguous chunk of blocks per XCD
__device__ __forceinline__ int xcd_swizzle(int orig, int nwg){
  const int q = nwg >> 3, r = nwg & 7;
  const int xcd = orig & 7, wg = orig >> 3;
  const int base = (xcd < r) ? xcd * (q + 1) : r * (q + 1) + (xcd - r) * q;
  return base + wg;
}

// ---------------- embedding
__global__ __launch_bounds__(256) void embed_kernel(
    const int* __restrict__ idx, const float* __restrict__ tok,
    const float* __restrict__ pos, float* __restrict__ x)
{
  const int bt = blockIdx.x;
  const int t  = bt & (Tx - 1);
  const int tid = threadIdx.x;
  const int tk = idx[bt];
  float4 a = *(const float4*)&tok[((size_t)tk << 10) + (tid << 2)];
  const float4 p = *(const float4*)&pos[((size_t)t << 10) + (tid << 2)];
  a.x += p.x; a.y += p.y; a.z += p.z; a.w += p.w;
  *(float4*)&x[((size_t)bt << 10) + (tid << 2)] = a;
}

// ---------------- layernorm: fp32 row -> bf16 row
__global__ __launch_bounds__(256) void ln_kernel(
    const float* __restrict__ x, const float* __restrict__ g,
    const float* __restrict__ b, short* __restrict__ out)
{
  const int row = blockIdx.x;
  const int tid = threadIdx.x;
  const float4 v = *(const float4*)&x[((size_t)row << 10) + (tid << 2)];
  float s  = v.x + v.y + v.z + v.w;
  float ss = v.x*v.x + v.y*v.y + v.z*v.z + v.w*v.w;
  #pragma unroll
  for (int off = 32; off >= 1; off >>= 1) {
    s  += __shfl_down(s, off);
    ss += __shfl_down(ss, off);
  }
  __shared__ float rs[4], rss[4];
  const int lane = tid & 63, w = tid >> 6;
  if (lane == 0) { rs[w] = s; rss[w] = ss; }
  __syncthreads();
  s  = rs[0] + rs[1] + rs[2] + rs[3];
  ss = rss[0] + rss[1] + rss[2] + rss[3];
  const float mu  = s * (1.0f / Cx);
  const float var = ss * (1.0f / Cx) - mu * mu;
  const float rstd = rsqrtf(var + 1e-5f);
  const float4 g4 = *(const float4*)&g[tid << 2];
  const float4 b4 = *(const float4*)&b[tid << 2];
  short4 o;
  o.x = f2bf((v.x - mu) * rstd * g4.x + b4.x);
  o.y = f2bf((v.y - mu) * rstd * g4.y + b4.y);
  o.z = f2bf((v.z - mu) * rstd * g4.z + b4.z);
  o.w = f2bf((v.w - mu) * rstd * g4.w + b4.w);
  *(short4*)&out[((size_t)row << 10) + (tid << 2)] = o;
}

// ---------------- weight convert+transpose: fp32 [K,N] -> bf16 [N,K]
__global__ __launch_bounds__(256) void wconv_kernel(
    const float* __restrict__ W, short* __restrict__ Wt, int K, int N)
{
  __shared__ float tile[32][33];
  const int n0 = blockIdx.x << 5, k0 = blockIdx.y << 5;
  const int tx = threadIdx.x & 31, ty = threadIdx.x >> 5;
  #pragma unroll
  for (int r = 0; r < 4; ++r)
    tile[ty + (r << 3)][tx] = __builtin_nontemporal_load(
        &W[(size_t)(k0 + ty + (r << 3)) * N + n0 + tx]);
  __syncthreads();
  #pragma unroll
  for (int r = 0; r < 4; ++r)
    Wt[(size_t)(n0 + ty + (r << 3)) * K + k0 + tx] = f2bf(tile[tx][ty + (r << 3)]);
}

// ---------------- GEMM (m97 structure) + XCD swizzle
// MODE 0: store bf16 to q/k/v layout [3][B,H,T,DH] (N=3072 fused QKV)
// MODE 1: outF = res + acc + bias (fp32)
// MODE 2: outB = bf16(gelu(acc + bias))
// MODE 3: outF = acc + bias (fp32, nontemporal — head logits)
template<int MODE>
__global__ __launch_bounds__(256) void gemm_kernel(
    const short* __restrict__ A, const short* __restrict__ Bt,
    const float* __restrict__ bias, const float* __restrict__ res,
    float* __restrict__ outF, short* __restrict__ outB, int N, int K)
{
  __shared__ __align__(16) short sA[128 * 32];
  __shared__ __align__(16) short sB[128 * 32];
  const int tid  = threadIdx.x;
  const int lane = tid & 63;
  const int wave = tid >> 6;
  const int ntile = N >> 7;
  const int bid  = xcd_swizzle((int)blockIdx.x, (int)gridDim.x);
  const int tm = (bid / ntile) << 7;
  const int tn = (bid % ntile) << 7;
  const int wm = ((wave >> 1) & 1) << 6;
  const int wn = (wave & 1) << 6;

  f32x4 acc[4][4] = {};

  const int o1  = tid << 4;
  const int row = o1 >> 6;
  const int col = (o1 & 63) >> 1;
  const short* gA1 = A  + (size_t)(tm + row) * K + col;
  const short* gA2 = A  + (size_t)(tm + row + 64) * K + col;
  const short* gB1 = Bt + (size_t)(tn + row) * K + col;
  const short* gB2 = Bt + (size_t)(tn + row + 64) * K + col;
  short* lA1 = sA + (wave << 9);
  short* lA2 = sA + 2048 + (wave << 9);
  short* lB1 = sB + (wave << 9);
  short* lB2 = sB + 2048 + (wave << 9);

  for (int k0 = 0; k0 < K; k0 += 32) {
    gload_lds16(gA1 + k0, lA1);
    gload_lds16(gA2 + k0, lA2);
    gload_lds16(gB1 + k0, lB1);
    gload_lds16(gB2 + k0, lB2);
    __syncthreads();
    bf16x8 aF[4], bF[4];
    const int kb = (lane >> 4) << 3;
    const int rsel = lane & 15;
    #pragma unroll
    for (int m = 0; m < 4; ++m)
      aF[m] = *(const bf16x8*)&sA[(wm + m * 16 + rsel) * 32 + kb];
    #pragma unroll
    for (int n = 0; n < 4; ++n)
      bF[n] = *(const bf16x8*)&sB[(wn + n * 16 + rsel) * 32 + kb];
    #pragma unroll
    for (int m = 0; m < 4; ++m) {
      #pragma unroll
      for (int n = 0; n < 4; ++n)
        acc[m][n] = __builtin_amdgcn_mfma_f32_16x16x32_bf16(aF[m], bF[n], acc[m][n], 0, 0, 0);
    }
    __syncthreads();
  }

  const int r0 = (lane >> 4) << 2;
  const int c0 = lane & 15;
  #pragma unroll
  for (int m = 0; m < 4; ++m) {
    #pragma unroll
    for (int n = 0; n < 4; ++n) {
      #pragma unroll
      for (int r = 0; r < 4; ++r) {
        const int grow = tm + wm + m * 16 + r0 + r;
        const int gcol = tn + wn + n * 16 + c0;
        const float v = acc[m][n][r];
        if constexpr (MODE == 0) {
          const int which = gcol >> 10;       // 0=q 1=k 2=v
          const int cc = gcol & 1023;
          const int b = grow >> 10, t = grow & 1023;
          const int hh = cc >> 6, d = cc & 63;
          outB[(size_t)which * (BTx * Cx) +
               ((size_t)((((b << 4) + hh) << 10) + t) << 6) + d] = f2bf(v);
        } else if constexpr (MODE == 1) {
          const size_t o = (size_t)grow * N + gcol;
          outF[o] = res[o] + v + bias[gcol];
        } else if constexpr (MODE == 2) {
          const float t2 = v + bias[gcol];
          const float gl = 0.5f * t2 * (1.0f + erff(t2 * 0.7071067811865475f));
          outB[(size_t)grow * N + gcol] = f2bf(gl);
        } else {
          __builtin_nontemporal_store(v + bias[gcol], &outF[(size_t)grow * N + gcol]);
        }
      }
    }
  }
}

// ---------------- flash attention (MFMA): q,k,v bf16 [B,H,T,DH] -> att [B,T,C]
__global__ __launch_bounds__(256) void fattn_kernel(
    const short* __restrict__ q, const short* __restrict__ k,
    const short* __restrict__ v, short* __restrict__ att)
{
  __shared__ __align__(16) short sQ[4096];
  __shared__ __align__(16) short sK[4096];
  __shared__ __align__(16) short sVT[4096];
  __shared__ __align__(16) short sP[4][1024];

  const int tid  = threadIdx.x;
  const int lane = tid & 63;
  const int w    = tid >> 6;
  const int r15  = lane & 15;
  const int g4   = lane >> 4;
  const int bid  = xcd_swizzle((int)blockIdx.x, (int)gridDim.x);
  const int qt   = bid & 15;
  const int bh   = bid >> 4;

  const char* Qb = (const char*)(q + ((size_t)bh << 16)) + ((size_t)qt << 13);
  const char* Kb = (const char*)(k + ((size_t)bh << 16));
  const char* Vb = (const char*)(v + ((size_t)bh << 16));

  const int X0  = tid << 4;
  const int X1  = X0 + 4096;
  const int sw0 = X0 ^ (((X0 >> 7) & 7) << 4);
  const int sw1 = X1 ^ (((X1 >> 7) & 7) << 4);
  const int ldsOff0 = (w << 10);
  const int ldsOff1 = (w << 10) + 4096;

  gload_lds16((const short*)(Qb + sw0), (short*)((char*)sQ + ldsOff0));
  gload_lds16((const short*)(Qb + sw1), (short*)((char*)sQ + ldsOff1));
  __syncthreads();
  bf16x8 aQ[2];
  {
    const int qrow = (w << 4) + r15;
    const int base = qrow * 128 + (g4 << 4);
    const int sz = (qrow & 7) << 4;
    aQ[0] = *(const bf16x8*)((char*)sQ + ((base     ) ^ sz));
    aQ[1] = *(const bf16x8*)((char*)sQ + ((base + 64) ^ sz));
  }

  const int vdh  = (lane & 31) << 1;
  const int vkv0 = (((w << 1) + (lane >> 5)) << 3);
  const int vb0  = (vdh * 128 + vkv0 * 2)       ^ ((vdh & 7) << 4);
  const int vb1  = ((vdh + 1) * 128 + vkv0 * 2) ^ (((vdh + 1) & 7) << 4);

  float m[4] = {-3e38f, -3e38f, -3e38f, -3e38f};
  float l[4] = {0.f, 0.f, 0.f, 0.f};
  f32x4 acc_o[4] = {};
  const int qrow_g0 = (qt << 6) + (w << 4) + (g4 << 2);

  for (int kt = 0; kt <= qt; ++kt) {
    __syncthreads();
    const char* Kt = Kb + ((size_t)kt << 13);
    gload_lds16((const short*)(Kt + sw0), (short*)((char*)sK + ldsOff0));
    gload_lds16((const short*)(Kt + sw1), (short*)((char*)sK + ldsOff1));
    {
      const char* Vt = Vb + ((size_t)kt << 13);
      unsigned uv[8];
      #pragma unroll
      for (int j = 0; j < 8; ++j)
        uv[j] = *(const unsigned*)(Vt + ((vkv0 + j) << 7) + (vdh << 1));
      short8 plo, phi;
      #pragma unroll
      for (int j = 0; j < 8; ++j) {
        plo[j] = (short)(uv[j] & 0xffffu);
        phi[j] = (short)(uv[j] >> 16);
      }
      *(short8*)((char*)sVT + vb0) = plo;
      *(short8*)((char*)sVT + vb1) = phi;
    }
    __syncthreads();

    f32x4 s[4] = {};
    #pragma unroll
    for (int f = 0; f < 4; ++f) {
      const int kv = (f << 4) + r15;
      const int kb = kv * 128 + (g4 << 4);
      const int sz = (kv & 7) << 4;
      const bf16x8 b0 = *(const bf16x8*)((char*)sK + ((kb     ) ^ sz));
      const bf16x8 b1 = *(const bf16x8*)((char*)sK + ((kb + 64) ^ sz));
      s[f] = __builtin_amdgcn_mfma_f32_16x16x32_bf16(aQ[0], b0, s[f], 0, 0, 0);
      s[f] = __builtin_amdgcn_mfma_f32_16x16x32_bf16(aQ[1], b1, s[f], 0, 0, 0);
    }
    #pragma unroll
    for (int f = 0; f < 4; ++f) {
      #pragma unroll
      for (int r = 0; r < 4; ++r) {
        float sv = s[f][r] * 0.125f;
        if ((kt << 6) + (f << 4) + r15 > qrow_g0 + r) sv = -3e38f;
        s[f][r] = sv;
      }
    }
    #pragma unroll
    for (int r = 0; r < 4; ++r) {
      float mx = fmaxf(fmaxf(s[0][r], s[1][r]), fmaxf(s[2][r], s[3][r]));
      mx = fmaxf(mx, __shfl_xor(mx, 1));
      mx = fmaxf(mx, __shfl_xor(mx, 2));
      mx = fmaxf(mx, __shfl_xor(mx, 4));
      mx = fmaxf(mx, __shfl_xor(mx, 8));
      const float mn = fmaxf(m[r], mx);
      const float e  = __expf(m[r] - mn);
      float sum = 0.f;
      #pragma unroll
      for (int f = 0; f < 4; ++f) {
        const float p = __expf(s[f][r] - mn);
        s[f][r] = p; sum += p;
      }
      sum += __shfl_xor(sum, 1);
      sum += __shfl_xor(sum, 2);
      sum += __shfl_xor(sum, 4);
      sum += __shfl_xor(sum, 8);
      l[r] = l[r] * e + sum;
      m[r] = mn;
      acc_o[0][r] *= e; acc_o[1][r] *= e; acc_o[2][r] *= e; acc_o[3][r] *= e;
    }
    short* Pw = sP[w];
    #pragma unroll
    for (int f = 0; f < 4; ++f) {
      #pragma unroll
      for (int r = 0; r < 4; ++r) {
        const int prow = (g4 << 2) + r;
        const int byte = prow * 128 + (((f << 4) + r15) << 1);
        *(short*)((char*)Pw + (byte ^ ((prow & 7) << 4))) = f2bf(s[f][r]);
      }
    }
    #pragma unroll
    for (int ks = 0; ks < 2; ++ks) {
      const int ab = r15 * 128 + (ks << 6) + (g4 << 4);
      const bf16x8 aP = *(const bf16x8*)((char*)Pw + (ab ^ ((r15 & 7) << 4)));
      #pragma unroll
      for (int f = 0; f < 4; ++f) {
        const int dh = (f << 4) + r15;
        const int bb = dh * 128 + (ks << 6) + (g4 << 4);
        const bf16x8 bV = *(const bf16x8*)((char*)sVT + (bb ^ ((dh & 7) << 4)));
        acc_o[f] = __builtin_amdgcn_mfma_f32_16x16x32_bf16(aP, bV, acc_o[f], 0, 0, 0);
      }
    }
  }

  const int b = bh >> 4, hh = bh & 15;
  #pragma unroll
  for (int f = 0; f < 4; ++f) {
    #pragma unroll
    for (int r = 0; r < 4; ++r) {
      const int qg = qrow_g0 + r;
      const int dh = (f << 4) + r15;
      att[((size_t)((b << 10) + qg) << 10) + (hh << 6) + dh] = f2bf(acc_o[f][r] / l[r]);
    }
  }
}

// ---------------- cross-entropy
__global__ void ce_zero_kernel(float* accum){ accum[0] = 0.0f; accum[1] = 0.0f; }

__global__ __launch_bounds__(256) void ce_row_kernel(
    const float* __restrict__ logits, const int* __restrict__ tgt, float* __restrict__ accum)
{
  const int row = blockIdx.x;
  const float* lg = logits + (size_t)row * Vx;
  const int tid = threadIdx.x;
  float m = -1e30f, ssum = 0.0f;
  for (int i = tid; i < Vx; i += 256) {
    const float v2 = __builtin_nontemporal_load(&lg[i]);
    const float nm = fmaxf(m, v2);
    ssum = ssum * __expf(m - nm) + __expf(v2 - nm);
    m = nm;
  }
  #pragma unroll
  for (int off = 32; off >= 1; off >>= 1) {
    const float om = __shfl_down(m, off), os = __shfl_down(ssum, off);
    const float nm = fmaxf(m, om);
    ssum = ssum * __expf(m - nm) + os * __expf(om - nm);
    m = nm;
  }
  __shared__ float ms[4], sss[4];
  if ((tid & 63) == 0) { ms[tid >> 6] = m; sss[tid >> 6] = ssum; }
  __syncthreads();
  if (tid == 0) {
    float M = ms[0], S = sss[0];
    #pragma unroll
    for (int i = 1; i < 4; ++i) {
      const float nm = fmaxf(M, ms[i]);
      S = S * __expf(M - nm) + sss[i] * __expf(ms[i] - nm);
      M = nm;
    }
    const int tg = tgt[row];
    if (tg != 5) {
      const float lt = lg[tg];
      const float nll = -(lt - M - logf(S));
      atomicAdd(&accum[0], nll);
      atomicAdd(&accum[1], 1.0f);
    }
  }
}

__global__ void ce_final_kernel(const float* __restrict__ accum, float* __restrict__ out)
{
  out[131072000ull] = accum[0] / fmaxf(accum[1], 1.0f);
}

// ---------------- host
extern "C" void kernel_launch(void* const* d_in, const int* in_sizes, int n_in,
                              void* d_out, int out_size, void* d_ws, size_t ws_size,
                              hipStream_t stream)
{
  const int*   idx     = (const int*)d_in[0];
  const int*   targets = (const int*)d_in[1];
  const float* tok_emb = (const float*)d_in[2];
  const float* pos_emb = (const float*)d_in[3];
  const float* Wq      = (const float*)d_in[4];
  const float* Wk      = (const float*)d_in[5];
  const float* Wv      = (const float*)d_in[6];
  const float* Wo      = (const float*)d_in[7];
  const float* bo      = (const float*)d_in[8];
  const float* ln1_g   = (const float*)d_in[9];
  const float* ln1_b   = (const float*)d_in[10];
  const float* ln2_g   = (const float*)d_in[11];
  const float* ln2_b   = (const float*)d_in[12];
  const float* W1      = (const float*)d_in[13];
  const float* b1      = (const float*)d_in[14];
  const float* W2      = (const float*)d_in[15];
  const float* b2      = (const float*)d_in[16];
  const float* lnf_g   = (const float*)d_in[17];
  const float* lnf_b   = (const float*)d_in[18];
  const float* Whead   = (const float*)d_in[19];
  const float* bhead   = (const float*)d_in[20];
  float* out = (float*)d_out;

  char* ws = (char*)d_ws;
  size_t off = 0;
  auto alloc = [&](size_t bytes) -> char* {
    char* p = ws + off;
    off += (bytes + 255) & ~(size_t)255;
    return p;
  };
  float* x    = (float*)alloc((size_t)BTx * Cx * 4);
  short* h    = (short*)alloc((size_t)BTx * Cx * 2);
  char*  blk  = ws + off;
  short* qb   = (short*)alloc((size_t)BTx * Cx * 2);   // qb,kb,vb contiguous
  short* kb   = (short*)alloc((size_t)BTx * Cx * 2);
  short* vb   = (short*)alloc((size_t)BTx * Cx * 2);
  short* attb = (short*)alloc((size_t)BTx * Cx * 2);
  short* ffb  = (short*)alloc((size_t)BTx * FFx * 2);
  short* wheadT = (short*)blk;
  short* wqkvT = (short*)alloc((size_t)3 * Cx * Cx * 2);  // [3072][1024] fused
  short* woT  = (short*)alloc((size_t)Cx * Cx * 2);
  short* w1T  = (short*)alloc((size_t)Cx * FFx * 2);
  short* w2T  = (short*)alloc((size_t)FFx * Cx * 2);
  float* accum = (float*)alloc(256);
  if (ws_size < off) return;
  short* wqT = wqkvT;
  short* wkT = wqkvT + (size_t)Cx * Cx;
  short* wvT = wqkvT + (size_t)2 * Cx * Cx;

  embed_kernel<<<BTx, 256, 0, stream>>>(idx, tok_emb, pos_emb, x);
  ce_zero_kernel<<<1, 1, 0, stream>>>(accum);

  for (int i = 0; i < Lx; ++i) {
    const size_t wo_off = (size_t)i * Cx * Cx;
    const size_t w1_off = (size_t)i * Cx * FFx;
    wconv_kernel<<<dim3(Cx / 32, Cx / 32), 256, 0, stream>>>(Wq + wo_off, wqT, Cx, Cx);
    wconv_kernel<<<dim3(Cx / 32, Cx / 32), 256, 0, stream>>>(Wk + wo_off, wkT, Cx, Cx);
    wconv_kernel<<<dim3(Cx / 32, Cx / 32), 256, 0, stream>>>(Wv + wo_off, wvT, Cx, Cx);
    wconv_kernel<<<dim3(Cx / 32, Cx / 32), 256, 0, stream>>>(Wo + wo_off, woT, Cx, Cx);
    wconv_kernel<<<dim3(FFx / 32, Cx / 32), 256, 0, stream>>>(W1 + w1_off, w1T, Cx, FFx);
    wconv_kernel<<<dim3(Cx / 32, FFx / 32), 256, 0, stream>>>(W2 + w1_off, w2T, FFx, Cx);

    ln_kernel<<<BTx, 256, 0, stream>>>(x, ln1_g + i * Cx, ln1_b + i * Cx, h);
    gemm_kernel<0><<<(BTx / 128) * (3 * Cx / 128), 256, 0, stream>>>(h, wqkvT, nullptr, nullptr, nullptr, qb, 3 * Cx, Cx);
    fattn_kernel<<<Bx * Hx * (Tx / 64), 256, 0, stream>>>(qb, kb, vb, attb);
    gemm_kernel<1><<<(BTx / 128) * (Cx / 128), 256, 0, stream>>>(attb, woT, bo + i * Cx, x, x, nullptr, Cx, Cx);

    ln_kernel<<<BTx, 256, 0, stream>>>(x, ln2_g + i * Cx, ln2_b + i * Cx, h);
    gemm_kernel<2><<<(BTx / 128) * (FFx / 128), 256, 0, stream>>>(h, w1T, b1 + i * FFx, nullptr, nullptr, ffb, FFx, Cx);
    gemm_kernel<1><<<(BTx / 128) * (Cx / 128), 256, 0, stream>>>(ffb, w2T, b2 + i * Cx, x, x, nullptr, Cx, FFx);
  }

  ln_kernel<<<BTx, 256, 0, stream>>>(x, lnf_g, lnf_b, h);
  wconv_kernel<<<dim3(Vx / 32, Cx / 32), 256, 0, stream>>>(Whead, wheadT, Cx, Vx);
  gemm_kernel<3><<<(BTx / 128) * (Vx / 128), 256, 0, stream>>>(h, wheadT, bhead, nullptr, out, nullptr, Vx, Cx);

  ce_row_kernel<<<BTx, 256, 0, stream>>>(out, targets, accum);
  ce_final_kernel<<<1, 1, 0, stream>>>(accum, out);
}